// Round 1
// baseline (911.875 us; speedup 1.0000x reference)
//
#include <hip/hip_runtime.h>
#include <hip/hip_bf16.h>
#include <stdint.h>

// Problem dims (hardcoded from reference):
// B=256, T=100, D=2*34*34=2312, H=1000, O=10.  ALL tensors fp32.
#define T_STEPS 100
#define B_SZ    256
#define D_IN    2312
#define H_SZ    1000
#define O_SZ    10
#define M_ROWS  (B_SZ * T_STEPS)   // 25600
#define K_PAD   2336               // 73 * 32 (W pre-split padded)
#define KT      73
#define W_ROWS  1024               // H padded to 1024 rows (rows >= 1000 zeroed)

// fp16 split scaling keeps lo-parts out of f16 subnormals.
// A*16 (|a|<6), W*64 (|w|<0.022).  Epilogue scale = 1/1024 (exact pow2).
#define A_SCALE   16.0f
#define W_SCALE   64.0f
#define INV_SCALE (1.0f / 1024.0f)

typedef __attribute__((ext_vector_type(4))) float     floatx4;
typedef __attribute__((ext_vector_type(8))) _Float16  halfx8;

#define ASYNC_COPY16(g, l)                                             \
  __builtin_amdgcn_global_load_lds(                                    \
      (const __attribute__((address_space(1))) void*)(g),              \
      (__attribute__((address_space(3))) void*)(l), 16, 0, 0)

// ---------------------------------------------------------------------------
// W pre-split: fp32 -> f16 hi/lo, scaled by 64, rows padded to K_PAD/W_ROWS.
// ---------------------------------------------------------------------------
__global__ __launch_bounds__(256)
void splitW_kernel(const float* __restrict__ W,    // [H_SZ, D_IN]
                   _Float16* __restrict__ wHi,     // [W_ROWS, K_PAD]
                   _Float16* __restrict__ wLo)
{
  const int r = blockIdx.x;
  const bool rvalid = (r < H_SZ);
  const float* w = W + (size_t)(rvalid ? r : 0) * D_IN;
  _Float16* ho = wHi + (size_t)r * K_PAD;
  _Float16* lo = wLo + (size_t)r * K_PAD;
  for (int c = threadIdx.x; c < K_PAD / 8; c += 256) {
    const int k0 = c * 8;
    const bool v = rvalid && (k0 + 8 <= D_IN);
    _Float16 h[8], l[8];
    #pragma unroll
    for (int e = 0; e < 8; ++e) {
      const float x = v ? w[k0 + e] * W_SCALE : 0.f;
      const _Float16 hb = (_Float16)x;
      h[e] = hb;
      l[e] = (_Float16)(x - (float)hb);
    }
    *reinterpret_cast<uint4*>(ho + k0) = *reinterpret_cast<const uint4*>(h);
    *reinterpret_cast<uint4*>(lo + k0) = *reinterpret_cast<const uint4*>(l);
  }
}

// ---------------------------------------------------------------------------
// Phase 1 (fused): cur1 = (A*16 fp32->f16split @ Wsplit) / 1024 + b1.
// 128x128 tile, BK=32, 4 waves 64x64, 3-pass split-f16 MFMA.
// Round-6 changes vs the 884.7us kernel:
//  (1) XCD-aware block remap: flat id%8 = XCD (measured round-robin).  Each
//      XCD owns a contiguous band of 25 m-slabs, n fastest within the band,
//      so the 8 blocks sharing one 128-row A slab are co-resident on ONE
//      XCD's L2 (was: spread over all 8 XCDs -> ~4x A over-fetch, FETCH
//      975 MB vs 247 MB ideal).
//  (2) Pipelined K-loop (T3/T4-lite): W double-buffered in LDS, DMA for
//      tile kt+1 issued BEFORE tile kt's MFMA phase, raw s_barrier with
//      counted s_waitcnt vmcnt(8) instead of __syncthreads' vmcnt(0) drain.
//      A prefetch is branch-free (clamped addr + validity flag) so per-wave
//      vmcnt bookkeeping stays uniform.
// Numerics are bit-identical to the previous version (same MFMA order).
// ---------------------------------------------------------------------------
__global__ __launch_bounds__(256)
void gemm1_fused(const float* __restrict__ A,       // [M_ROWS, D_IN] fp32
                 const _Float16* __restrict__ wHi,  // [W_ROWS, K_PAD]
                 const _Float16* __restrict__ wLo,
                 const float* __restrict__ b1,      // [H_SZ]
                 float* __restrict__ C)             // [M_ROWS, H_SZ]
{
  __shared__ _Float16 sAh[128 * 32];
  __shared__ _Float16 sAl[128 * 32];
  __shared__ _Float16 sBh[2][128 * 32];
  __shared__ _Float16 sBl[2][128 * 32];

  const int tid  = threadIdx.x;

  // XCD-aware remap (bijective: 1600 = 8 XCDs x 200).
  const int id  = blockIdx.x;            // 0..1599, XCD = id & 7
  const int j   = id >> 3;               // 0..199
  const int mt  = (id & 7) * 25 + (j >> 3);
  const int nt  = j & 7;
  const int m0  = mt * 128;
  const int n0  = nt * 128;

  const int wid  = tid >> 6;
  const int lane = tid & 63;
  const int wm   = (wid & 1) * 64;
  const int wn   = (wid >> 1) * 64;
  const int quad = lane >> 4;
  const int l16  = lane & 15;

  floatx4 acc[4][4];
  #pragma unroll
  for (int i = 0; i < 4; ++i)
    #pragma unroll
    for (int jj = 0; jj < 4; ++jj)
      acc[i][jj] = floatx4{0.f, 0.f, 0.f, 0.f};

  // Staging map: thread tid owns rows r0=tid>>2 and r1=r0+64, LDS slot tid&3.
  // Swizzle: slot s of row r holds global chunk s ^ rho(r), rho(r)=(r>>1)&3.
  const int r0  = tid >> 2;
  const int r1  = r0 + 64;
  const int sl  = tid & 3;
  const int rho = (r0 >> 1) & 3;
  const int ko  = ((sl ^ rho) * 8);   // swizzled global chunk offset (elements)

  const float* gA0 = A + (size_t)(m0 + r0) * D_IN + ko;
  const float* gA1 = A + (size_t)(m0 + r1) * D_IN + ko;
  const _Float16* gBh0 = wHi + (size_t)(n0 + r0) * K_PAD + ko;
  const _Float16* gBh1 = wHi + (size_t)(n0 + r1) * K_PAD + ko;
  const _Float16* gBl0 = wLo + (size_t)(n0 + r0) * K_PAD + ko;
  const _Float16* gBl1 = wLo + (size_t)(n0 + r1) * K_PAD + ko;

  _Float16* lAh0 = sAh + (size_t)tid * 8;
  _Float16* lAh1 = sAh + (size_t)(tid + 256) * 8;
  _Float16* lAl0 = sAl + (size_t)tid * 8;
  _Float16* lAl1 = sAl + (size_t)(tid + 256) * 8;
  const int lb0 = tid * 8;          // B LDS element offsets (per buffer)
  const int lb1 = (tid + 256) * 8;

  // Fragment-read swizzle offset (elements).
  const int fo = (quad ^ ((l16 >> 1) & 3)) * 8;

  // ---- Prologue.  Order matters for vmcnt bookkeeping: A loads first,
  // then the 4 W DMAs.  Invariant at loop top: exactly the current tile's
  // 4 W DMAs are the oldest outstanding vmem ops (behind the 4 A loads,
  // which the compiler drains with its own vmcnt(4) before the split).
  float a0[8], a1[8];
  *reinterpret_cast<float4*>(a0)     = *reinterpret_cast<const float4*>(gA0);
  *reinterpret_cast<float4*>(a0 + 4) = *reinterpret_cast<const float4*>(gA0 + 4);
  *reinterpret_cast<float4*>(a1)     = *reinterpret_cast<const float4*>(gA1);
  *reinterpret_cast<float4*>(a1 + 4) = *reinterpret_cast<const float4*>(gA1 + 4);
  bool curValid = true;             // ko+8 <= 32 <= D_IN always for tile 0

  ASYNC_COPY16(gBh0, &sBh[0][lb0]);
  ASYNC_COPY16(gBh1, &sBh[0][lb1]);
  ASYNC_COPY16(gBl0, &sBl[0][lb0]);
  ASYNC_COPY16(gBl1, &sBl[0][lb1]);

  for (int kt = 0; kt < KT; ++kt) {
    const int p = kt & 1;

    // ---- (1) in-register split of A(kt) -> LDS.  Compiler inserts
    // vmcnt(4) before the first use of a0/a1 (leaves the W DMAs in flight).
    {
      _Float16 h0[8], l0[8], h1[8], l1[8];
      #pragma unroll
      for (int e = 0; e < 8; ++e) {
        const float v0 = curValid ? a0[e] * A_SCALE : 0.f;
        const _Float16 hb0 = (_Float16)v0;
        h0[e] = hb0; l0[e] = (_Float16)(v0 - (float)hb0);
        const float v1 = curValid ? a1[e] * A_SCALE : 0.f;
        const _Float16 hb1 = (_Float16)v1;
        h1[e] = hb1; l1[e] = (_Float16)(v1 - (float)hb1);
      }
      *reinterpret_cast<uint4*>(lAh0) = *reinterpret_cast<const uint4*>(h0);
      *reinterpret_cast<uint4*>(lAl0) = *reinterpret_cast<const uint4*>(l0);
      *reinterpret_cast<uint4*>(lAh1) = *reinterpret_cast<const uint4*>(h1);
      *reinterpret_cast<uint4*>(lAl1) = *reinterpret_cast<const uint4*>(l1);
    }

    // ---- (2) prefetch tile kt+1: A regs (branch-free, clamped) then W DMA
    // into the other buffer.  These 8 vmem ops stay outstanding across the
    // barrier; vmcnt(8) drains only W(kt) (the oldest 4).
    if (kt + 1 < KT) {
      const int kb = (kt + 1) * 32;
      const bool v = (kb + ko) < D_IN;       // chunk fully valid (D_IN%8==0)
      const int off = v ? kb : 0;            // clamp: always issue 4 loads
      *reinterpret_cast<float4*>(a0)     = *reinterpret_cast<const float4*>(gA0 + off);
      *reinterpret_cast<float4*>(a0 + 4) = *reinterpret_cast<const float4*>(gA0 + off + 4);
      *reinterpret_cast<float4*>(a1)     = *reinterpret_cast<const float4*>(gA1 + off);
      *reinterpret_cast<float4*>(a1 + 4) = *reinterpret_cast<const float4*>(gA1 + off + 4);
      curValid = v;
      ASYNC_COPY16(gBh0 + kb, &sBh[p ^ 1][lb0]);
      ASYNC_COPY16(gBh1 + kb, &sBh[p ^ 1][lb1]);
      ASYNC_COPY16(gBl0 + kb, &sBl[p ^ 1][lb0]);
      ASYNC_COPY16(gBl1 + kb, &sBl[p ^ 1][lb1]);
      asm volatile("s_waitcnt vmcnt(8) lgkmcnt(0)" ::: "memory");
    } else {
      asm volatile("s_waitcnt vmcnt(0) lgkmcnt(0)" ::: "memory");
    }
    __builtin_amdgcn_s_barrier();
    asm volatile("" ::: "memory");     // no LDS reads hoist above the barrier

    // ---- (3) fragments + 48 MFMA from buffer p.
    halfx8 ah[4], bh[4], al[4], bl[4];
    #pragma unroll
    for (int i = 0; i < 4; ++i) {
      const int row = (wm + i * 16 + l16) * 32 + fo;
      ah[i] = *reinterpret_cast<const halfx8*>(sAh + row);
      al[i] = *reinterpret_cast<const halfx8*>(sAl + row);
    }
    #pragma unroll
    for (int jj = 0; jj < 4; ++jj) {
      const int row = (wn + jj * 16 + l16) * 32 + fo;
      bh[jj] = *reinterpret_cast<const halfx8*>(&sBh[p][row]);
      bl[jj] = *reinterpret_cast<const halfx8*>(&sBl[p][row]);
    }
    #pragma unroll
    for (int i = 0; i < 4; ++i)
      #pragma unroll
      for (int jj = 0; jj < 4; ++jj)
        acc[i][jj] = __builtin_amdgcn_mfma_f32_16x16x32_f16(ah[i], bh[jj], acc[i][jj], 0, 0, 0);
    #pragma unroll
    for (int i = 0; i < 4; ++i)
      #pragma unroll
      for (int jj = 0; jj < 4; ++jj)
        acc[i][jj] = __builtin_amdgcn_mfma_f32_16x16x32_f16(al[i], bh[jj], acc[i][jj], 0, 0, 0);
    #pragma unroll
    for (int i = 0; i < 4; ++i)
      #pragma unroll
      for (int jj = 0; jj < 4; ++jj)
        acc[i][jj] = __builtin_amdgcn_mfma_f32_16x16x32_f16(ah[i], bl[jj], acc[i][jj], 0, 0, 0);

    // ---- (4) tail barrier: next iter's ds_write to sA* and DMA into
    // sB*[p^1] must not start until every wave finished reading them.
    asm volatile("" ::: "memory");
    __builtin_amdgcn_s_barrier();
    asm volatile("" ::: "memory");
  }

  // Epilogue: C/D layout col = lane&15, row = quad*4 + reg (m89/m91 verified).
  #pragma unroll
  for (int jj = 0; jj < 4; ++jj) {
    const int col = n0 + wn + jj * 16 + l16;
    if (col < H_SZ) {
      const float bias = b1[col];
      #pragma unroll
      for (int i = 0; i < 4; ++i) {
        const int row = m0 + wm + i * 16 + quad * 4;
        #pragma unroll
        for (int r = 0; r < 4; ++r)
          C[(size_t)(row + r) * H_SZ + col] = acc[i][jj][r] * INV_SCALE + bias;
      }
    }
  }
}

// ---------------------------------------------------------------------------
// Phase 2a: layer-1 LIF scan. One thread per (b,h) chain.
// ---------------------------------------------------------------------------
__global__ __launch_bounds__(256)
void scan1_kernel(const float* __restrict__ cur1,     // [B, T, H] fp32
                  const float* __restrict__ beta_p,
                  __hip_bfloat16* __restrict__ spk1)  // [B, T, H] bf16 (0/1)
{
  const int h = blockIdx.x * 256 + threadIdx.x;
  const int b = blockIdx.y;
  if (h >= H_SZ) return;
  const float beta = beta_p[0];
  const float* c    = cur1 + (size_t)b * T_STEPS * H_SZ + h;
  __hip_bfloat16* s = spk1 + (size_t)b * T_STEPS * H_SZ + h;
  float mem = 0.f, spk = 0.f;
  #pragma unroll 4
  for (int t = 0; t < T_STEPS; ++t) {
    mem = beta * mem + c[(size_t)t * H_SZ] - spk;
    spk = (mem > 1.0f) ? 1.0f : 0.0f;
    s[(size_t)t * H_SZ] = __float2bfloat16(spk);
  }
}

// ---------------------------------------------------------------------------
// Phase 2b: cur2[m][o] = sum_h spk1[m][h] * w2[o][h].  Wave per row m.
// Spikes are exactly 0/1 -> accumulate w2 where spike!=0 (exact).
// ---------------------------------------------------------------------------
__global__ __launch_bounds__(256)
void gemm2_kernel(const __hip_bfloat16* __restrict__ spk1, // [M_ROWS, H]
                  const float* __restrict__ w2,            // [O, H] fp32
                  float* __restrict__ cur2)                // [M_ROWS, O]
{
  const int wid  = threadIdx.x >> 6;
  const int lane = threadIdx.x & 63;
  const int m    = blockIdx.x * 4 + wid;

  float acc[O_SZ];
  #pragma unroll
  for (int o = 0; o < O_SZ; ++o) acc[o] = 0.f;

  const __hip_bfloat16* row = spk1 + (size_t)m * H_SZ;
  #pragma unroll
  for (int it = 0; it < 16; ++it) {
    const int h = it * 64 + lane;
    if (h < H_SZ) {
      const float s = __bfloat162float(row[h]);
      if (s != 0.f) {
        #pragma unroll
        for (int o = 0; o < O_SZ; ++o)
          acc[o] += w2[o * H_SZ + h];
      }
    }
  }
  #pragma unroll
  for (int o = 0; o < O_SZ; ++o) {
    float v = acc[o];
    #pragma unroll
    for (int off = 32; off > 0; off >>= 1) v += __shfl_down(v, off);
    if (lane == 0) cur2[(size_t)m * O_SZ + o] = v;
  }
}

// ---------------------------------------------------------------------------
// Phase 2c: layer-2 scan + write outputs (fp32).
// ---------------------------------------------------------------------------
__global__ __launch_bounds__(256)
void scan2_kernel(const float* __restrict__ cur2,   // [B*T, O]
                  const float* __restrict__ b2,
                  const float* __restrict__ beta_p,
                  float* __restrict__ out)
{
  const int idx = blockIdx.x * 256 + threadIdx.x;
  if (idx >= B_SZ * O_SZ) return;
  const int b = idx / O_SZ;
  const int o = idx % O_SZ;
  const float beta = beta_p[0];
  const float bias = b2[o];
  float* spk_rec = out;
  float* mem_rec = out + (size_t)T_STEPS * B_SZ * O_SZ;
  float mem = 0.f, spk = 0.f;
  for (int t = 0; t < T_STEPS; ++t) {
    const float cur = cur2[((size_t)b * T_STEPS + t) * O_SZ + o] + bias;
    mem = beta * mem + cur - spk;
    spk = (mem > 1.0f) ? 1.0f : 0.0f;
    const size_t oi = ((size_t)t * B_SZ + b) * O_SZ + o;
    spk_rec[oi] = spk;
    mem_rec[oi] = mem;
  }
}

// ---------------------------------------------------------------------------
extern "C" void kernel_launch(void* const* d_in, const int* in_sizes, int n_in,
                              void* d_out, int out_size, void* d_ws, size_t ws_size,
                              hipStream_t stream)
{
  const float* data = (const float*)d_in[0]; // [B,T,2,34,34] -> [25600, 2312]
  const float* w1   = (const float*)d_in[1]; // [1000, 2312]
  const float* b1   = (const float*)d_in[2]; // [1000]
  const float* w2   = (const float*)d_in[3]; // [10, 1000]
  const float* b2   = (const float*)d_in[4]; // [10]
  const float* beta = (const float*)d_in[5]; // [1]
  float* out = (float*)d_out;                // 2 * [100,256,10] fp32

  // Workspace (fixed, ~164 MB):
  //   wHi, wLo : f16 [1024, 2336]  = 4.78 MB each
  //   cur1     : fp32 [25600,1000] = 102.4 MB
  //   spk1     : bf16 [25600,1000] = 51.2 MB
  //   cur2     : fp32 [25600,10]   = 1.02 MB
  char* p = (char*)d_ws;
  auto take = [&](size_t n) { char* q = p; p += (n + 255) & ~(size_t)255; return q; };
  _Float16*       wHi  = (_Float16*)take((size_t)W_ROWS * K_PAD * 2);
  _Float16*       wLo  = (_Float16*)take((size_t)W_ROWS * K_PAD * 2);
  float*          cur1 = (float*)take((size_t)M_ROWS * H_SZ * 4);
  __hip_bfloat16* spk1 = (__hip_bfloat16*)take((size_t)M_ROWS * H_SZ * 2);
  float*          cur2 = (float*)take((size_t)M_ROWS * O_SZ * 4);

  splitW_kernel<<<dim3(W_ROWS), 256, 0, stream>>>(w1, wHi, wLo);
  gemm1_fused<<<dim3(1600), 256, 0, stream>>>(data, wHi, wLo, b1, cur1);
  scan1_kernel<<<dim3(4, B_SZ), 256, 0, stream>>>(cur1, beta, spk1);
  gemm2_kernel<<<dim3(M_ROWS / 4), 256, 0, stream>>>(spk1, w2, cur2);
  scan2_kernel<<<dim3(10), 256, 0, stream>>>(cur2, b2, beta, out);
}

// Round 2
// 820.962 us; speedup vs baseline: 1.1107x; 1.1107x over previous
//
#include <hip/hip_runtime.h>
#include <hip/hip_bf16.h>
#include <stdint.h>

// Problem dims (hardcoded from reference):
// B=256, T=100, D=2*34*34=2312, H=1000, O=10.  ALL tensors fp32.
#define T_STEPS 100
#define B_SZ    256
#define D_IN    2312
#define H_SZ    1000
#define O_SZ    10
#define M_ROWS  (B_SZ * T_STEPS)   // 25600
#define K_PAD   2336               // 73 * 32 (W pre-split padded)
#define KT      73
#define W_ROWS  1024               // H padded to 1024 rows (rows >= 1000 zeroed)

// fp16 split scaling keeps lo-parts out of f16 subnormals.
// A*16 (|a|<6), W*64 (|w|<0.022).  Epilogue scale = 1/1024 (exact pow2).
#define A_SCALE   16.0f
#define W_SCALE   64.0f
#define INV_SCALE (1.0f / 1024.0f)

typedef __attribute__((ext_vector_type(4))) float     floatx4;
typedef __attribute__((ext_vector_type(8))) _Float16  halfx8;

#define ASYNC_COPY16(g, l)                                             \
  __builtin_amdgcn_global_load_lds(                                    \
      (const __attribute__((address_space(1))) void*)(g),              \
      (__attribute__((address_space(3))) void*)(l), 16, 0, 0)

// ---------------------------------------------------------------------------
// W pre-split: fp32 -> f16 hi/lo, scaled by 64, rows padded to K_PAD/W_ROWS.
// ---------------------------------------------------------------------------
__global__ __launch_bounds__(256)
void splitW_kernel(const float* __restrict__ W,    // [H_SZ, D_IN]
                   _Float16* __restrict__ wHi,     // [W_ROWS, K_PAD]
                   _Float16* __restrict__ wLo)
{
  const int r = blockIdx.x;
  const bool rvalid = (r < H_SZ);
  const float* w = W + (size_t)(rvalid ? r : 0) * D_IN;
  _Float16* ho = wHi + (size_t)r * K_PAD;
  _Float16* lo = wLo + (size_t)r * K_PAD;
  for (int c = threadIdx.x; c < K_PAD / 8; c += 256) {
    const int k0 = c * 8;
    const bool v = rvalid && (k0 + 8 <= D_IN);
    _Float16 h[8], l[8];
    #pragma unroll
    for (int e = 0; e < 8; ++e) {
      const float x = v ? w[k0 + e] * W_SCALE : 0.f;
      const _Float16 hb = (_Float16)x;
      h[e] = hb;
      l[e] = (_Float16)(x - (float)hb);
    }
    *reinterpret_cast<uint4*>(ho + k0) = *reinterpret_cast<const uint4*>(h);
    *reinterpret_cast<uint4*>(lo + k0) = *reinterpret_cast<const uint4*>(l);
  }
}

// ---------------------------------------------------------------------------
// Phase 1 (fused): cur1 = (A*16 fp32->f16split @ Wsplit) / 1024 + b1.
// 128x128 tile, BK=32, 4 waves 64x64, 3-pass split-f16 MFMA.
//
// Round-7 structure (post-mortem of the counted-vmcnt regression):
//  * FULL double-buffer: sA AND sB are [2] buffers.  Iter kt reads tile kt
//    from [p], writes tile kt+1 (A reg-split + W DMA) into [p^1], and
//    prefetches A(kt+2) into registers.  The old single-buffered sA forced
//    a ds_write -> barrier -> ds_read chain onto the critical path every
//    iteration; that chain is gone.
//  * ONE __syncthreads per iter (loop top).  Its implicit vmcnt(0)/lgkmcnt(0)
//    legally drains last iter's DMA + ds_writes, which had a full MFMA phase
//    of cover.  Fragment ds_reads are issued BEFORE any DMA of the same
//    iter, so compiler-conservative vmcnt waits before them are free --
//    this is what the round-6 counted-vmcnt scheme got wrong (the compiler
//    inserted vmcnt(0) before reads aliasing the just-issued DMAs).
//  * No inline asm.  XCD-aware remap kept (FETCH 975 MB -> 269 MB verified).
// Numerics bit-identical (same MFMA order): absmax must stay 0.03125.
// ---------------------------------------------------------------------------
__global__ __launch_bounds__(256)
void gemm1_fused(const float* __restrict__ A,       // [M_ROWS, D_IN] fp32
                 const _Float16* __restrict__ wHi,  // [W_ROWS, K_PAD]
                 const _Float16* __restrict__ wLo,
                 const float* __restrict__ b1,      // [H_SZ]
                 float* __restrict__ C)             // [M_ROWS, H_SZ]
{
  __shared__ _Float16 sAh[2][128 * 32];   // 16 KB each pair-member set
  __shared__ _Float16 sAl[2][128 * 32];
  __shared__ _Float16 sBh[2][128 * 32];
  __shared__ _Float16 sBl[2][128 * 32];   // total 64 KB -> 2 blocks/CU

  const int tid  = threadIdx.x;

  // XCD-aware remap (bijective: 1600 = 8 XCDs x 200).
  const int id  = blockIdx.x;            // 0..1599, XCD = id & 7
  const int j   = id >> 3;               // 0..199
  const int mt  = (id & 7) * 25 + (j >> 3);
  const int nt  = j & 7;
  const int m0  = mt * 128;
  const int n0  = nt * 128;

  const int wid  = tid >> 6;
  const int lane = tid & 63;
  const int wm   = (wid & 1) * 64;
  const int wn   = (wid >> 1) * 64;
  const int quad = lane >> 4;
  const int l16  = lane & 15;

  floatx4 acc[4][4];
  #pragma unroll
  for (int i = 0; i < 4; ++i)
    #pragma unroll
    for (int jj = 0; jj < 4; ++jj)
      acc[i][jj] = floatx4{0.f, 0.f, 0.f, 0.f};

  // Staging map: thread tid owns rows r0=tid>>2 and r1=r0+64, LDS slot tid&3.
  // Swizzle: slot s of row r holds global chunk s ^ rho(r), rho(r)=(r>>1)&3.
  const int r0  = tid >> 2;
  const int r1  = r0 + 64;
  const int sl  = tid & 3;
  const int rho = (r0 >> 1) & 3;
  const int ko  = ((sl ^ rho) * 8);   // swizzled global chunk offset (elements)

  const float* gA0 = A + (size_t)(m0 + r0) * D_IN + ko;
  const float* gA1 = A + (size_t)(m0 + r1) * D_IN + ko;
  const _Float16* gBh0 = wHi + (size_t)(n0 + r0) * K_PAD + ko;
  const _Float16* gBh1 = wHi + (size_t)(n0 + r1) * K_PAD + ko;
  const _Float16* gBl0 = wLo + (size_t)(n0 + r0) * K_PAD + ko;
  const _Float16* gBl1 = wLo + (size_t)(n0 + r1) * K_PAD + ko;

  const int la0 = tid * 8;          // per-buffer LDS element offsets
  const int la1 = (tid + 256) * 8;

  // Fragment-read swizzle offset (elements).
  const int fo = (quad ^ ((l16 >> 1) & 3)) * 8;

  // ---- Prologue: tile 0 into buffers [0]; A(1) into registers.
  float a0[8], a1[8];
  *reinterpret_cast<float4*>(a0)     = *reinterpret_cast<const float4*>(gA0);
  *reinterpret_cast<float4*>(a0 + 4) = *reinterpret_cast<const float4*>(gA0 + 4);
  *reinterpret_cast<float4*>(a1)     = *reinterpret_cast<const float4*>(gA1);
  *reinterpret_cast<float4*>(a1 + 4) = *reinterpret_cast<const float4*>(gA1 + 4);

  ASYNC_COPY16(gBh0, &sBh[0][la0]);
  ASYNC_COPY16(gBh1, &sBh[0][la1]);
  ASYNC_COPY16(gBl0, &sBl[0][la0]);
  ASYNC_COPY16(gBl1, &sBl[0][la1]);

  {
    _Float16 h0[8], l0[8], h1[8], l1[8];
    #pragma unroll
    for (int e = 0; e < 8; ++e) {
      const float v0 = a0[e] * A_SCALE;
      const _Float16 hb0 = (_Float16)v0;
      h0[e] = hb0; l0[e] = (_Float16)(v0 - (float)hb0);
      const float v1 = a1[e] * A_SCALE;
      const _Float16 hb1 = (_Float16)v1;
      h1[e] = hb1; l1[e] = (_Float16)(v1 - (float)hb1);
    }
    *reinterpret_cast<uint4*>(&sAh[0][la0]) = *reinterpret_cast<const uint4*>(h0);
    *reinterpret_cast<uint4*>(&sAl[0][la0]) = *reinterpret_cast<const uint4*>(l0);
    *reinterpret_cast<uint4*>(&sAh[0][la1]) = *reinterpret_cast<const uint4*>(h1);
    *reinterpret_cast<uint4*>(&sAl[0][la1]) = *reinterpret_cast<const uint4*>(l1);
  }

  // A(1) into registers (always fully in-bounds: 32 + ko + 8 <= 64 < D_IN).
  *reinterpret_cast<float4*>(a0)     = *reinterpret_cast<const float4*>(gA0 + 32);
  *reinterpret_cast<float4*>(a0 + 4) = *reinterpret_cast<const float4*>(gA0 + 36);
  *reinterpret_cast<float4*>(a1)     = *reinterpret_cast<const float4*>(gA1 + 32);
  *reinterpret_cast<float4*>(a1 + 4) = *reinterpret_cast<const float4*>(gA1 + 36);
  bool curValid = true;

  for (int kt = 0; kt < KT; ++kt) {
    const int p = kt & 1;

    // Drains last iter's ds_writes + W DMA (full MFMA phase of cover) and
    // publishes buffers [p] to all waves.
    __syncthreads();

    // ---- (1) fragment reads of tile kt from [p] -- before any DMA this
    // iter, so no outstanding vmem op can force a stall here.
    halfx8 ah[4], bh[4], al[4], bl[4];
    #pragma unroll
    for (int i = 0; i < 4; ++i) {
      const int row = (wm + i * 16 + l16) * 32 + fo;
      ah[i] = *reinterpret_cast<const halfx8*>(&sAh[p][row]);
      al[i] = *reinterpret_cast<const halfx8*>(&sAl[p][row]);
    }
    #pragma unroll
    for (int jj = 0; jj < 4; ++jj) {
      const int row = (wn + jj * 16 + l16) * 32 + fo;
      bh[jj] = *reinterpret_cast<const halfx8*>(&sBh[p][row]);
      bl[jj] = *reinterpret_cast<const halfx8*>(&sBl[p][row]);
    }

    // ---- (2) stage tile kt+1 into [p^1]: A reg-split + ds_write, W DMA.
    if (kt + 1 < KT) {
      _Float16 h0[8], l0[8], h1[8], l1[8];
      #pragma unroll
      for (int e = 0; e < 8; ++e) {
        const float v0 = curValid ? a0[e] * A_SCALE : 0.f;
        const _Float16 hb0 = (_Float16)v0;
        h0[e] = hb0; l0[e] = (_Float16)(v0 - (float)hb0);
        const float v1 = curValid ? a1[e] * A_SCALE : 0.f;
        const _Float16 hb1 = (_Float16)v1;
        h1[e] = hb1; l1[e] = (_Float16)(v1 - (float)hb1);
      }
      const int q = p ^ 1;
      *reinterpret_cast<uint4*>(&sAh[q][la0]) = *reinterpret_cast<const uint4*>(h0);
      *reinterpret_cast<uint4*>(&sAl[q][la0]) = *reinterpret_cast<const uint4*>(l0);
      *reinterpret_cast<uint4*>(&sAh[q][la1]) = *reinterpret_cast<const uint4*>(h1);
      *reinterpret_cast<uint4*>(&sAl[q][la1]) = *reinterpret_cast<const uint4*>(l1);

      const int kb = (kt + 1) * 32;
      ASYNC_COPY16(gBh0 + kb, &sBh[q][la0]);
      ASYNC_COPY16(gBh1 + kb, &sBh[q][la1]);
      ASYNC_COPY16(gBl0 + kb, &sBl[q][la0]);
      ASYNC_COPY16(gBl1 + kb, &sBl[q][la1]);
    }

    // ---- (3) prefetch A(kt+2) into registers (branch-free clamp).
    if (kt + 2 < KT) {
      const int kb2 = (kt + 2) * 32;
      const bool v = (kb2 + ko) < D_IN;      // chunk fully valid (D_IN%8==0)
      const int off = v ? kb2 : 0;
      *reinterpret_cast<float4*>(a0)     = *reinterpret_cast<const float4*>(gA0 + off);
      *reinterpret_cast<float4*>(a0 + 4) = *reinterpret_cast<const float4*>(gA0 + off + 4);
      *reinterpret_cast<float4*>(a1)     = *reinterpret_cast<const float4*>(gA1 + off);
      *reinterpret_cast<float4*>(a1 + 4) = *reinterpret_cast<const float4*>(gA1 + off + 4);
      curValid = v;
    }

    // ---- (4) 48 MFMA on tile kt (same order as before: hh, lh, hl).
    #pragma unroll
    for (int i = 0; i < 4; ++i)
      #pragma unroll
      for (int jj = 0; jj < 4; ++jj)
        acc[i][jj] = __builtin_amdgcn_mfma_f32_16x16x32_f16(ah[i], bh[jj], acc[i][jj], 0, 0, 0);
    #pragma unroll
    for (int i = 0; i < 4; ++i)
      #pragma unroll
      for (int jj = 0; jj < 4; ++jj)
        acc[i][jj] = __builtin_amdgcn_mfma_f32_16x16x32_f16(al[i], bh[jj], acc[i][jj], 0, 0, 0);
    #pragma unroll
    for (int i = 0; i < 4; ++i)
      #pragma unroll
      for (int jj = 0; jj < 4; ++jj)
        acc[i][jj] = __builtin_amdgcn_mfma_f32_16x16x32_f16(ah[i], bl[jj], acc[i][jj], 0, 0, 0);
  }

  // Epilogue: C/D layout col = lane&15, row = quad*4 + reg (m89/m91 verified).
  #pragma unroll
  for (int jj = 0; jj < 4; ++jj) {
    const int col = n0 + wn + jj * 16 + l16;
    if (col < H_SZ) {
      const float bias = b1[col];
      #pragma unroll
      for (int i = 0; i < 4; ++i) {
        const int row = m0 + wm + i * 16 + quad * 4;
        #pragma unroll
        for (int r = 0; r < 4; ++r)
          C[(size_t)(row + r) * H_SZ + col] = acc[i][jj][r] * INV_SCALE + bias;
      }
    }
  }
}

// ---------------------------------------------------------------------------
// Phase 2a: layer-1 LIF scan. One thread per (b,h) chain.
// ---------------------------------------------------------------------------
__global__ __launch_bounds__(256)
void scan1_kernel(const float* __restrict__ cur1,     // [B, T, H] fp32
                  const float* __restrict__ beta_p,
                  __hip_bfloat16* __restrict__ spk1)  // [B, T, H] bf16 (0/1)
{
  const int h = blockIdx.x * 256 + threadIdx.x;
  const int b = blockIdx.y;
  if (h >= H_SZ) return;
  const float beta = beta_p[0];
  const float* c    = cur1 + (size_t)b * T_STEPS * H_SZ + h;
  __hip_bfloat16* s = spk1 + (size_t)b * T_STEPS * H_SZ + h;
  float mem = 0.f, spk = 0.f;
  #pragma unroll 4
  for (int t = 0; t < T_STEPS; ++t) {
    mem = beta * mem + c[(size_t)t * H_SZ] - spk;
    spk = (mem > 1.0f) ? 1.0f : 0.0f;
    s[(size_t)t * H_SZ] = __float2bfloat16(spk);
  }
}

// ---------------------------------------------------------------------------
// Phase 2b: cur2[m][o] = sum_h spk1[m][h] * w2[o][h].  Wave per row m.
// Spikes are exactly 0/1 -> accumulate w2 where spike!=0 (exact).
// ---------------------------------------------------------------------------
__global__ __launch_bounds__(256)
void gemm2_kernel(const __hip_bfloat16* __restrict__ spk1, // [M_ROWS, H]
                  const float* __restrict__ w2,            // [O, H] fp32
                  float* __restrict__ cur2)                // [M_ROWS, O]
{
  const int wid  = threadIdx.x >> 6;
  const int lane = threadIdx.x & 63;
  const int m    = blockIdx.x * 4 + wid;

  float acc[O_SZ];
  #pragma unroll
  for (int o = 0; o < O_SZ; ++o) acc[o] = 0.f;

  const __hip_bfloat16* row = spk1 + (size_t)m * H_SZ;
  #pragma unroll
  for (int it = 0; it < 16; ++it) {
    const int h = it * 64 + lane;
    if (h < H_SZ) {
      const float s = __bfloat162float(row[h]);
      if (s != 0.f) {
        #pragma unroll
        for (int o = 0; o < O_SZ; ++o)
          acc[o] += w2[o * H_SZ + h];
      }
    }
  }
  #pragma unroll
  for (int o = 0; o < O_SZ; ++o) {
    float v = acc[o];
    #pragma unroll
    for (int off = 32; off > 0; off >>= 1) v += __shfl_down(v, off);
    if (lane == 0) cur2[(size_t)m * O_SZ + o] = v;
  }
}

// ---------------------------------------------------------------------------
// Phase 2c: layer-2 scan + write outputs (fp32).
// ---------------------------------------------------------------------------
__global__ __launch_bounds__(256)
void scan2_kernel(const float* __restrict__ cur2,   // [B*T, O]
                  const float* __restrict__ b2,
                  const float* __restrict__ beta_p,
                  float* __restrict__ out)
{
  const int idx = blockIdx.x * 256 + threadIdx.x;
  if (idx >= B_SZ * O_SZ) return;
  const int b = idx / O_SZ;
  const int o = idx % O_SZ;
  const float beta = beta_p[0];
  const float bias = b2[o];
  float* spk_rec = out;
  float* mem_rec = out + (size_t)T_STEPS * B_SZ * O_SZ;
  float mem = 0.f, spk = 0.f;
  for (int t = 0; t < T_STEPS; ++t) {
    const float cur = cur2[((size_t)b * T_STEPS + t) * O_SZ + o] + bias;
    mem = beta * mem + cur - spk;
    spk = (mem > 1.0f) ? 1.0f : 0.0f;
    const size_t oi = ((size_t)t * B_SZ + b) * O_SZ + o;
    spk_rec[oi] = spk;
    mem_rec[oi] = mem;
  }
}

// ---------------------------------------------------------------------------
extern "C" void kernel_launch(void* const* d_in, const int* in_sizes, int n_in,
                              void* d_out, int out_size, void* d_ws, size_t ws_size,
                              hipStream_t stream)
{
  const float* data = (const float*)d_in[0]; // [B,T,2,34,34] -> [25600, 2312]
  const float* w1   = (const float*)d_in[1]; // [1000, 2312]
  const float* b1   = (const float*)d_in[2]; // [1000]
  const float* w2   = (const float*)d_in[3]; // [10, 1000]
  const float* b2   = (const float*)d_in[4]; // [10]
  const float* beta = (const float*)d_in[5]; // [1]
  float* out = (float*)d_out;                // 2 * [100,256,10] fp32

  // Workspace (fixed, ~164 MB):
  //   wHi, wLo : f16 [1024, 2336]  = 4.78 MB each
  //   cur1     : fp32 [25600,1000] = 102.4 MB
  //   spk1     : bf16 [25600,1000] = 51.2 MB
  //   cur2     : fp32 [25600,10]   = 1.02 MB
  char* p = (char*)d_ws;
  auto take = [&](size_t n) { char* q = p; p += (n + 255) & ~(size_t)255; return q; };
  _Float16*       wHi  = (_Float16*)take((size_t)W_ROWS * K_PAD * 2);
  _Float16*       wLo  = (_Float16*)take((size_t)W_ROWS * K_PAD * 2);
  float*          cur1 = (float*)take((size_t)M_ROWS * H_SZ * 4);
  __hip_bfloat16* spk1 = (__hip_bfloat16*)take((size_t)M_ROWS * H_SZ * 2);
  float*          cur2 = (float*)take((size_t)M_ROWS * O_SZ * 4);

  splitW_kernel<<<dim3(W_ROWS), 256, 0, stream>>>(w1, wHi, wLo);
  gemm1_fused<<<dim3(1600), 256, 0, stream>>>(data, wHi, wLo, b1, cur1);
  scan1_kernel<<<dim3(4, B_SZ), 256, 0, stream>>>(cur1, beta, spk1);
  gemm2_kernel<<<dim3(M_ROWS / 4), 256, 0, stream>>>(spk1, w2, cur2);
  scan2_kernel<<<dim3(10), 256, 0, stream>>>(cur2, b2, beta, out);
}